// Round 2
// baseline (111.758 us; speedup 1.0000x reference)
//
#include <hip/hip_runtime.h>
#include <math.h>

#define TOPK_N 3
#define IOU_THR 0.5f

__device__ __forceinline__ bool better(float va, int ia, float vb, int ib) {
    // lax.top_k ordering: higher value first; ties -> lower index first
    return (va > vb) || (va == vb && ia < ib);
}

// One block, 256 threads. Computes:
//  - scatter_m2s via prefix-sum of num_targets (jnp.repeat semantics incl. pad-with-last)
//  - rows/cols compaction of mask2d (int32!) in row-major order, padded with (0,0)
//    stored as rcidx[j] = r*N + c, starts[j] = r/N, ends[j] = (c+1)/N
//  - identity flag (compaction is identity <=> all mask true)
//  - zeroes the two double accumulators
__global__ void init_kernel(const int* __restrict__ num_targets,
                            const int* __restrict__ mask2d,
                            int* __restrict__ scatter,
                            int* __restrict__ rcidx,
                            float* __restrict__ starts,
                            float* __restrict__ ends,
                            double* __restrict__ sums,
                            int* __restrict__ flag,
                            int S, int M, int N, int P) {
    __shared__ int cum[1025];   // supports S <= 1024
    __shared__ int tsum[256];
    __shared__ int ex[257];
    const int tid = threadIdx.x;

    if (tid < 2) sums[tid] = 0.0;

    if (tid == 0) {
        int acc = 0;
        cum[0] = 0;
        for (int s = 0; s < S; ++s) { acc += num_targets[s]; cum[s + 1] = acc; }
    }
    __syncthreads();
    const int total = cum[S];

    // scatter_m2s[m] = video index for target m (binary search in cumsum)
    for (int m = tid; m < M; m += 256) {
        int mm = m;
        if (mm >= total) mm = (total > 0) ? (total - 1) : 0;  // pad with final value
        int lo = 0, hi = S - 1;
        while (lo < hi) {
            int mid = (lo + hi) >> 1;
            if (cum[mid + 1] <= mm) lo = mid + 1; else hi = mid;
        }
        scatter[m] = lo;
    }

    // mask2d compaction (row-major order preserved by per-thread contiguous chunks)
    const int per = (P + 255) / 256;
    const int base = tid * per;
    int cnt = 0;
    for (int k = 0; k < per; ++k) {
        int j = base + k;
        if (j < P && mask2d[j] != 0) cnt++;
    }
    tsum[tid] = cnt;
    __syncthreads();
    if (tid == 0) {
        int a = 0;
        for (int i = 0; i < 256; ++i) { ex[i] = a; a += tsum[i]; }
        ex[256] = a;
    }
    __syncthreads();

    int pos = ex[tid];
    const float fN = (float)N;
    for (int k = 0; k < per; ++k) {
        int j = base + k;
        if (j < P && mask2d[j] != 0) {
            int r = j / N;
            int c = j - r * N;
            rcidx[pos] = j;                    // = r*N + c
            starts[pos] = (float)r / fN;       // exact same op as reference
            ends[pos]   = (float)(c + 1) / fN;
            pos++;
        }
    }
    __syncthreads();
    const int K = ex[256];
    for (int j = K + tid; j < P; j += 256) {   // nonzero(size=P) pads with index 0
        rcidx[j]  = 0;
        starts[j] = 0.0f;
        ends[j]   = 1.0f / fN;
    }
    if (tid == 0) flag[0] = (K == P && (P & 3) == 0) ? 1 : 0;
}

// One block per target row m. 256 threads.
__global__ __launch_bounds__(256)
void loss_kernel(const float* __restrict__ start_offset,
                 const float* __restrict__ end_offset,
                 const float* __restrict__ tgt_moments,
                 const int* __restrict__ scatter,
                 const float* __restrict__ iou2ds,
                 const int* __restrict__ rcidx,
                 const float* __restrict__ starts,
                 const float* __restrict__ ends,
                 double* __restrict__ sums,
                 const int* __restrict__ flag,
                 int P, int M) {
    // XCD-aware mapping: the 4 consecutive m sharing one start_offset row land
    // on the same XCD's L2 (blocks dispatch round-robin across 8 XCDs).
    int bid = blockIdx.x;
    const int m = ((M & 7) == 0) ? ((bid & 7) * (M >> 3) + (bid >> 3)) : bid;
    const int tid = threadIdx.x;
    const int s   = scatter[m];

    const float* __restrict__ so_row  = start_offset + (size_t)s * P;
    const float* __restrict__ eo_row  = end_offset   + (size_t)s * P;
    const float* __restrict__ iou_row = iou2ds       + (size_t)m * P;
    const float tgt0 = tgt_moments[2 * m];
    const float tgt1 = tgt_moments[2 * m + 1];

    double lsum = 0.0;
    int    lcnt = 0;

    // thread-local top-3 (sorted desc, stable)
    float v0 = -INFINITY, v1 = -INFINITY, v2 = -INFINITY;
    int   i0 = 0x7fffffff, i1 = 0x7fffffff, i2 = 0x7fffffff;

#define PROC(v, jj, so_, eo_, st_, en_)                                         \
    do {                                                                        \
        if (better(v, jj, v2, i2)) {                                            \
            if (better(v, jj, v1, i1)) {                                        \
                v2 = v1; i2 = i1;                                               \
                if (better(v, jj, v0, i0)) { v1 = v0; i1 = i0; v0 = v; i0 = jj; } \
                else                       { v1 = v;  i1 = jj; }                \
            } else { v2 = v; i2 = jj; }                                         \
        }                                                                       \
        if (v > IOU_THR) {                                                      \
            const float sot = tgt0 - (st_);                                     \
            const float eot = tgt1 - (en_);                                     \
            lsum += (double)(fabsf((so_) - sot) + fabsf((eo_) - eot));          \
            lcnt++;                                                             \
        }                                                                       \
    } while (0)

    if (flag[0]) {
        // identity compaction: fully vectorized float4 streaming
        const float4* __restrict__ iou4 = (const float4*)iou_row;
        const float4* __restrict__ so4  = (const float4*)so_row;
        const float4* __restrict__ eo4  = (const float4*)eo_row;
        const float4* __restrict__ st4  = (const float4*)starts;
        const float4* __restrict__ en4  = (const float4*)ends;
        const int P4 = P >> 2;
        for (int q = tid; q < P4; q += 256) {
            const float4 vi = iou4[q];
            const float4 vs = so4[q];
            const float4 ve = eo4[q];
            const float4 vt = st4[q];
            const float4 vn = en4[q];
            const int j = q << 2;
            PROC(vi.x, j + 0, vs.x, ve.x, vt.x, vn.x);
            PROC(vi.y, j + 1, vs.y, ve.y, vt.y, vn.y);
            PROC(vi.z, j + 2, vs.z, ve.z, vt.z, vn.z);
            PROC(vi.w, j + 3, vs.w, ve.w, vt.w, vn.w);
        }
    } else {
        for (int j = tid; j < P; j += 256) {
            const int   idx = rcidx[j];
            const float v   = iou_row[idx];
            PROC(v, j, so_row[j], eo_row[j], starts[j], ends[j]);
        }
    }
#undef PROC

    // block-level stable top-3 merge reduction
    __shared__ float sv[256][3];
    __shared__ int   si[256][3];
    sv[tid][0] = v0; sv[tid][1] = v1; sv[tid][2] = v2;
    si[tid][0] = i0; si[tid][1] = i1; si[tid][2] = i2;
    __syncthreads();

    for (int str = 128; str > 0; str >>= 1) {
        if (tid < str) {
            float av0 = sv[tid][0], av1 = sv[tid][1], av2 = sv[tid][2];
            int   ai0 = si[tid][0], ai1 = si[tid][1], ai2 = si[tid][2];
            float bv0 = sv[tid + str][0], bv1 = sv[tid + str][1], bv2 = sv[tid + str][2];
            int   bi0 = si[tid + str][0], bi1 = si[tid + str][1], bi2 = si[tid + str][2];

            bool t0 = better(av0, ai0, bv0, bi0);
            float ov0 = t0 ? av0 : bv0;  int oi0 = t0 ? ai0 : bi0;
            float ahv = t0 ? av1 : av0;  int ahi = t0 ? ai1 : ai0;
            float a2v = t0 ? av2 : av1;  int a2i = t0 ? ai2 : ai1;
            float bhv = t0 ? bv0 : bv1;  int bhi = t0 ? bi0 : bi1;
            float b2v = t0 ? bv1 : bv2;  int b2i = t0 ? bi1 : bi2;

            bool t1 = better(ahv, ahi, bhv, bhi);
            float ov1 = t1 ? ahv : bhv;  int oi1 = t1 ? ahi : bhi;
            float cav = t1 ? a2v : ahv;  int cai = t1 ? a2i : ahi;
            float cbv = t1 ? bhv : b2v;  int cbi = t1 ? bhi : b2i;

            bool t2 = better(cav, cai, cbv, cbi);
            float ov2 = t2 ? cav : cbv;  int oi2 = t2 ? cai : cbi;

            sv[tid][0] = ov0; sv[tid][1] = ov1; sv[tid][2] = ov2;
            si[tid][0] = oi0; si[tid][1] = oi1; si[tid][2] = oi2;
        }
        __syncthreads();
    }

    // top-3 entries not already counted by (iou > 0.5)
    if (tid < TOPK_N) {
        const float v = sv[0][tid];
        const int   j = si[0][tid];
        if (j != 0x7fffffff && !(v > IOU_THR)) {
            const float sot = tgt0 - starts[j];
            const float eot = tgt1 - ends[j];
            const float l = fabsf(so_row[j] - sot) + fabsf(eo_row[j] - eot);
            lsum += (double)l;
            lcnt++;
        }
    }

    // block sum reduction
    __shared__ double dsum[256];
    __shared__ int    dcnt[256];
    dsum[tid] = lsum; dcnt[tid] = lcnt;
    __syncthreads();
    for (int str = 128; str > 0; str >>= 1) {
        if (tid < str) { dsum[tid] += dsum[tid + str]; dcnt[tid] += dcnt[tid + str]; }
        __syncthreads();
    }
    if (tid == 0) {
        atomicAdd(&sums[0], dsum[0]);
        atomicAdd(&sums[1], (double)dcnt[0]);
    }
}

__global__ void finalize_kernel(const double* __restrict__ sums, float* __restrict__ out) {
    out[0] = (float)(sums[0] / sums[1]);
}

extern "C" void kernel_launch(void* const* d_in, const int* in_sizes, int n_in,
                              void* d_out, int out_size, void* d_ws, size_t ws_size,
                              hipStream_t stream) {
    const float* start_offset = (const float*)d_in[0];
    const float* end_offset   = (const float*)d_in[1];
    const float* tgt_moments  = (const float*)d_in[2];
    const int*   num_targets  = (const int*)d_in[3];
    const float* iou2ds       = (const float*)d_in[4];
    const int*   mask2d       = (const int*)d_in[5];   // bool pushed as int32

    const int S = in_sizes[3];
    const int M = in_sizes[2] / 2;
    const int P = in_sizes[0] / S;
    const int NN = in_sizes[5];
    int N = 1;
    while ((long long)N * N < (long long)NN) N++;

    // workspace layout (16B aligned blocks)
    char* ws = (char*)d_ws;
    double* sums = (double*)ws;                          // 2 doubles
    size_t off = 16;
    int*   flag    = (int*)(ws + off);    off += 16;
    int*   scatter = (int*)(ws + off);    off += ((size_t)M * 4 + 15) & ~(size_t)15;
    int*   rcidx   = (int*)(ws + off);    off += ((size_t)P * 4 + 15) & ~(size_t)15;
    float* starts  = (float*)(ws + off);  off += ((size_t)P * 4 + 15) & ~(size_t)15;
    float* ends    = (float*)(ws + off);  off += ((size_t)P * 4 + 15) & ~(size_t)15;

    init_kernel<<<1, 256, 0, stream>>>(num_targets, mask2d, scatter, rcidx,
                                       starts, ends, sums, flag, S, M, N, P);
    loss_kernel<<<M, 256, 0, stream>>>(start_offset, end_offset, tgt_moments, scatter,
                                       iou2ds, rcidx, starts, ends, sums, flag, P, M);
    finalize_kernel<<<1, 1, 0, stream>>>(sums, (float*)d_out);
}

// Round 3
// 90.114 us; speedup vs baseline: 1.2402x; 1.2402x over previous
//
#include <hip/hip_runtime.h>
#include <math.h>

#define TOPK_N 3
#define IOU_THR 0.5f
#define MAXN_TAB 2048   // fast path supports N <= 2048 (table in LDS)

__device__ __forceinline__ bool better(float va, int ia, float vb, int ib) {
    // lax.top_k ordering: higher value first; ties -> lower index first
    return (va > vb) || (va == vb && ia < ib);
}

// One block, 256 threads, fully parallel (no serial thread-0 global loops).
__global__ void init_kernel(const int* __restrict__ num_targets,
                            const int* __restrict__ mask2d,
                            int* __restrict__ scatter,
                            int* __restrict__ rcidx,
                            float* __restrict__ starts,
                            float* __restrict__ ends,
                            int* __restrict__ flag,
                            int S, int M, int N, int P) {
    __shared__ int cum[1025];   // supports S <= 1024
    __shared__ int scan[256];
    const int tid = threadIdx.x;

    // ---- parallel cumsum of num_targets ----
    const int chunk = (S + 255) / 256;   // <= 4 for S <= 1024
    const int sbase = tid * chunk;
    int local[4];
    int csum = 0;
    for (int k = 0; k < chunk && k < 4; ++k) {
        int s = sbase + k;
        int v = (s < S) ? num_targets[s] : 0;
        csum += v;
        local[k] = csum;                 // inclusive within chunk
    }
    scan[tid] = csum;
    __syncthreads();
    for (int d = 1; d < 256; d <<= 1) {  // Hillis-Steele inclusive scan
        int v = scan[tid];
        int add = (tid >= d) ? scan[tid - d] : 0;
        __syncthreads();
        scan[tid] = v + add;
        __syncthreads();
    }
    {
        int excl = scan[tid] - csum;
        for (int k = 0; k < chunk && k < 4; ++k) {
            int s = sbase + k;
            if (s < S) cum[s + 1] = excl + local[k];
        }
        if (tid == 0) cum[0] = 0;
    }
    __syncthreads();
    const int total = cum[S];

    // scatter_m2s[m] = video index for target m (binary search in cumsum)
    for (int m = tid; m < M; m += 256) {
        int mm = m;
        if (mm >= total) mm = (total > 0) ? (total - 1) : 0;  // jnp.repeat pad
        int lo = 0, hi = S - 1;
        while (lo < hi) {
            int mid = (lo + hi) >> 1;
            if (cum[mid + 1] <= mm) lo = mid + 1; else hi = mid;
        }
        scatter[m] = lo;
    }
    __syncthreads();

    // ---- mask2d compaction (parallel scan; int32 mask!) ----
    const int per = (P + 255) / 256;
    const int base = tid * per;
    int cnt = 0;
    for (int k = 0; k < per; ++k) {
        int j = base + k;
        if (j < P && mask2d[j] != 0) cnt++;
    }
    scan[tid] = cnt;
    __syncthreads();
    for (int d = 1; d < 256; d <<= 1) {
        int v = scan[tid];
        int add = (tid >= d) ? scan[tid - d] : 0;
        __syncthreads();
        scan[tid] = v + add;
        __syncthreads();
    }
    const int K = scan[255];
    int pos = scan[tid] - cnt;   // exclusive prefix

    const float fN = (float)N;
    for (int k = 0; k < per; ++k) {
        int j = base + k;
        if (j < P && mask2d[j] != 0) {
            int r = j / N;
            int c = j - r * N;
            rcidx[pos]  = j;
            starts[pos] = (float)r / fN;        // exact reference op
            ends[pos]   = (float)(c + 1) / fN;
            pos++;
        }
    }
    __syncthreads();
    for (int j = K + tid; j < P; j += 256) {    // nonzero(size=P) pads with index 0
        rcidx[j]  = 0;
        starts[j] = 0.0f;
        ends[j]   = 1.0f / fN;
    }
    if (tid == 0) flag[0] = (K == P && (P & 3) == 0 && N <= MAXN_TAB) ? 1 : 0;
}

// One block per target row m. 256 threads. Writes per-block partials (no atomics).
__global__ __launch_bounds__(256)
void loss_kernel(const float* __restrict__ start_offset,
                 const float* __restrict__ end_offset,
                 const float* __restrict__ tgt_moments,
                 const int* __restrict__ scatter,
                 const float* __restrict__ iou2ds,
                 const int* __restrict__ rcidx,
                 const float* __restrict__ starts,
                 const float* __restrict__ ends,
                 double* __restrict__ psum,
                 int* __restrict__ pcnt,
                 const int* __restrict__ flag,
                 int P, int M, int N) {
    // XCD-aware mapping: the 4 consecutive m sharing one start_offset row land
    // on the same XCD's L2 (blocks dispatch round-robin across 8 XCDs).
    const int bid = blockIdx.x;
    const int m = ((M & 7) == 0) ? ((bid & 7) * (M >> 3) + (bid >> 3)) : bid;
    const int tid = threadIdx.x;
    const int s   = scatter[m];
    const int fp  = flag[0];

    const float* __restrict__ so_row  = start_offset + (size_t)s * P;
    const float* __restrict__ eo_row  = end_offset   + (size_t)s * P;
    const float* __restrict__ iou_row = iou2ds       + (size_t)m * P;
    const float tgt0 = tgt_moments[2 * m];
    const float tgt1 = tgt_moments[2 * m + 1];

    // LDS tables for the identity-compaction fast path (bit-identical values)
    __shared__ float st_tab[MAXN_TAB];
    __shared__ float en_tab[MAXN_TAB];
    if (fp) {
        const float fN = (float)N;
        for (int i = tid; i < N; i += 256) {
            st_tab[i] = (float)i / fN;
            en_tab[i] = (float)(i + 1) / fN;
        }
        __syncthreads();
    }

    double lsum = 0.0;
    int    lcnt = 0;

    // thread-local top-3 (sorted desc, stable)
    float v0 = -INFINITY, v1 = -INFINITY, v2 = -INFINITY;
    int   i0 = 0x7fffffff, i1 = 0x7fffffff, i2 = 0x7fffffff;

#define PROC(v, jj, so_, eo_, st_, en_)                                         \
    do {                                                                        \
        if (better(v, jj, v2, i2)) {                                            \
            if (better(v, jj, v1, i1)) {                                        \
                v2 = v1; i2 = i1;                                               \
                if (better(v, jj, v0, i0)) { v1 = v0; i1 = i0; v0 = v; i0 = jj; } \
                else                       { v1 = v;  i1 = jj; }                \
            } else { v2 = v; i2 = jj; }                                         \
        }                                                                       \
        if (v > IOU_THR) {                                                      \
            const float sot = tgt0 - (st_);                                     \
            const float eot = tgt1 - (en_);                                     \
            lsum += (double)(fabsf((so_) - sot) + fabsf((eo_) - eot));          \
            lcnt++;                                                             \
        }                                                                       \
    } while (0)

    if (fp) {
        const float4* __restrict__ iou4 = (const float4*)iou_row;
        const float4* __restrict__ so4  = (const float4*)so_row;
        const float4* __restrict__ eo4  = (const float4*)eo_row;
        const int P4 = P >> 2;
        for (int q = tid; q < P4; q += 256) {
            const float4 vi = iou4[q];
            const float4 vs = so4[q];
            const float4 ve = eo4[q];
            const int j = q << 2;
            int r = j / N;            // one div per 4-element group
            int c = j - r * N;
            PROC(vi.x, j + 0, vs.x, ve.x, st_tab[r], en_tab[c]);
            c++; if (c == N) { c = 0; r++; }
            PROC(vi.y, j + 1, vs.y, ve.y, st_tab[r], en_tab[c]);
            c++; if (c == N) { c = 0; r++; }
            PROC(vi.z, j + 2, vs.z, ve.z, st_tab[r], en_tab[c]);
            c++; if (c == N) { c = 0; r++; }
            PROC(vi.w, j + 3, vs.w, ve.w, st_tab[r], en_tab[c]);
        }
    } else {
        for (int j = tid; j < P; j += 256) {
            const int   idx = rcidx[j];
            const float v   = iou_row[idx];
            PROC(v, j, so_row[j], eo_row[j], starts[j], ends[j]);
        }
    }
#undef PROC

    // block-level stable top-3 merge reduction
    __shared__ float sv[256][3];
    __shared__ int   si[256][3];
    sv[tid][0] = v0; sv[tid][1] = v1; sv[tid][2] = v2;
    si[tid][0] = i0; si[tid][1] = i1; si[tid][2] = i2;
    __syncthreads();

    for (int str = 128; str > 0; str >>= 1) {
        if (tid < str) {
            float av0 = sv[tid][0], av1 = sv[tid][1], av2 = sv[tid][2];
            int   ai0 = si[tid][0], ai1 = si[tid][1], ai2 = si[tid][2];
            float bv0 = sv[tid + str][0], bv1 = sv[tid + str][1], bv2 = sv[tid + str][2];
            int   bi0 = si[tid + str][0], bi1 = si[tid + str][1], bi2 = si[tid + str][2];

            bool t0 = better(av0, ai0, bv0, bi0);
            float ov0 = t0 ? av0 : bv0;  int oi0 = t0 ? ai0 : bi0;
            float ahv = t0 ? av1 : av0;  int ahi = t0 ? ai1 : ai0;
            float a2v = t0 ? av2 : av1;  int a2i = t0 ? ai2 : ai1;
            float bhv = t0 ? bv0 : bv1;  int bhi = t0 ? bi0 : bi1;
            float b2v = t0 ? bv1 : bv2;  int b2i = t0 ? bi1 : bi2;

            bool t1 = better(ahv, ahi, bhv, bhi);
            float ov1 = t1 ? ahv : bhv;  int oi1 = t1 ? ahi : bhi;
            float cav = t1 ? a2v : ahv;  int cai = t1 ? a2i : ahi;
            float cbv = t1 ? bhv : b2v;  int cbi = t1 ? bhi : b2i;

            bool t2 = better(cav, cai, cbv, cbi);
            float ov2 = t2 ? cav : cbv;  int oi2 = t2 ? cai : cbi;

            sv[tid][0] = ov0; sv[tid][1] = ov1; sv[tid][2] = ov2;
            si[tid][0] = oi0; si[tid][1] = oi1; si[tid][2] = oi2;
        }
        __syncthreads();
    }

    // top-3 entries not already counted by (iou > 0.5)
    if (tid < TOPK_N) {
        const float v = sv[0][tid];
        const int   j = si[0][tid];
        if (j != 0x7fffffff && !(v > IOU_THR)) {
            float stj, enj;
            if (fp) {
                int r = j / N, c = j - r * N;
                stj = st_tab[r]; enj = en_tab[c];
            } else {
                stj = starts[j]; enj = ends[j];
            }
            const float sot = tgt0 - stj;
            const float eot = tgt1 - enj;
            lsum += (double)(fabsf(so_row[j] - sot) + fabsf(eo_row[j] - eot));
            lcnt++;
        }
    }

    // block sum reduction -> per-block partials (no global atomics)
    __shared__ double dsum[256];
    __shared__ int    dcnt[256];
    dsum[tid] = lsum; dcnt[tid] = lcnt;
    __syncthreads();
    for (int str = 128; str > 0; str >>= 1) {
        if (tid < str) { dsum[tid] += dsum[tid + str]; dcnt[tid] += dcnt[tid + str]; }
        __syncthreads();
    }
    if (tid == 0) {
        psum[bid] = dsum[0];
        pcnt[bid] = dcnt[0];
    }
}

__global__ void finalize_kernel(const double* __restrict__ psum,
                                const int* __restrict__ pcnt,
                                int M, float* __restrict__ out) {
    __shared__ double sd[256];
    __shared__ int    sc[256];
    const int tid = threadIdx.x;
    double a = 0.0;
    int    c = 0;
    for (int i = tid; i < M; i += 256) { a += psum[i]; c += pcnt[i]; }
    sd[tid] = a; sc[tid] = c;
    __syncthreads();
    for (int str = 128; str > 0; str >>= 1) {
        if (tid < str) { sd[tid] += sd[tid + str]; sc[tid] += sc[tid + str]; }
        __syncthreads();
    }
    if (tid == 0) out[0] = (float)(sd[0] / (double)sc[0]);
}

extern "C" void kernel_launch(void* const* d_in, const int* in_sizes, int n_in,
                              void* d_out, int out_size, void* d_ws, size_t ws_size,
                              hipStream_t stream) {
    const float* start_offset = (const float*)d_in[0];
    const float* end_offset   = (const float*)d_in[1];
    const float* tgt_moments  = (const float*)d_in[2];
    const int*   num_targets  = (const int*)d_in[3];
    const float* iou2ds       = (const float*)d_in[4];
    const int*   mask2d       = (const int*)d_in[5];   // bool pushed as int32

    const int S = in_sizes[3];
    const int M = in_sizes[2] / 2;
    const int P = in_sizes[0] / S;
    const int NN = in_sizes[5];
    int N = 1;
    while ((long long)N * N < (long long)NN) N++;

    // workspace layout (16B aligned blocks)
    char* ws = (char*)d_ws;
    size_t off = 0;
    int*    flag    = (int*)(ws + off);    off += 16;
    int*    scatter = (int*)(ws + off);    off += ((size_t)M * 4 + 15) & ~(size_t)15;
    int*    rcidx   = (int*)(ws + off);    off += ((size_t)P * 4 + 15) & ~(size_t)15;
    float*  starts  = (float*)(ws + off);  off += ((size_t)P * 4 + 15) & ~(size_t)15;
    float*  ends    = (float*)(ws + off);  off += ((size_t)P * 4 + 15) & ~(size_t)15;
    double* psum    = (double*)(ws + off); off += ((size_t)M * 8 + 15) & ~(size_t)15;
    int*    pcnt    = (int*)(ws + off);    off += ((size_t)M * 4 + 15) & ~(size_t)15;

    init_kernel<<<1, 256, 0, stream>>>(num_targets, mask2d, scatter, rcidx,
                                       starts, ends, flag, S, M, N, P);
    loss_kernel<<<M, 256, 0, stream>>>(start_offset, end_offset, tgt_moments, scatter,
                                       iou2ds, rcidx, starts, ends, psum, pcnt,
                                       flag, P, M, N);
    finalize_kernel<<<1, 256, 0, stream>>>(psum, pcnt, M, (float*)d_out);
}

// Round 4
// 42.771 us; speedup vs baseline: 2.6130x; 2.1069x over previous
//
#include <hip/hip_runtime.h>
#include <math.h>

#define TOPK_N 3
#define IOU_THR 0.5f
#define MAXN_TAB 4096     // fast path supports N <= 4096 (dynamic LDS tables)
#define NCNT 64           // counting blocks in prep_kernel

__device__ __forceinline__ bool better(float va, int ia, float vb, int ib) {
    // lax.top_k ordering: higher value first; ties -> lower index first
    return (va > vb) || (va == vb && ia < ib);
}

// 65 blocks x 256 threads.
// Blocks 0..63: partial nonzero counts of mask2d (coalesced int4) -> counts[bid].
// Block 64: cumsum of num_targets + scatter_m2s (jnp.repeat semantics).
__global__ void prep_kernel(const int* __restrict__ num_targets,
                            const int* __restrict__ mask2d,
                            int* __restrict__ scatter,
                            int* __restrict__ counts,
                            int S, int M, int P) {
    const int bid = blockIdx.x;
    const int tid = threadIdx.x;

    if (bid < NCNT) {
        const int P4 = P >> 2;
        const int4* __restrict__ m4 = (const int4*)mask2d;
        int c = 0;
        for (int q = bid * 256 + tid; q < P4; q += NCNT * 256) {
            const int4 v = m4[q];
            c += (v.x != 0) + (v.y != 0) + (v.z != 0) + (v.w != 0);
        }
        if (bid == 0) {                       // scalar tail if P % 4 != 0
            for (int j = (P4 << 2) + tid; j < P; j += 256)
                c += (mask2d[j] != 0);
        }
        __shared__ int red[256];
        red[tid] = c;
        __syncthreads();
        for (int st = 128; st > 0; st >>= 1) {
            if (tid < st) red[tid] += red[tid + st];
            __syncthreads();
        }
        if (tid == 0) counts[bid] = red[0];
    } else {
        // ---- cumsum of num_targets (parallel) + scatter ----
        __shared__ int cum[1025];   // supports S <= 1024
        __shared__ int scn[256];
        const int chunk = (S + 255) / 256;   // <= 4 for S <= 1024
        const int sbase = tid * chunk;
        int local[4];
        int csum = 0;
        for (int k = 0; k < chunk && k < 4; ++k) {
            int s = sbase + k;
            int v = (s < S) ? num_targets[s] : 0;
            csum += v;
            local[k] = csum;                 // inclusive within chunk
        }
        scn[tid] = csum;
        __syncthreads();
        for (int d = 1; d < 256; d <<= 1) {  // Hillis-Steele inclusive scan
            int v = scn[tid];
            int add = (tid >= d) ? scn[tid - d] : 0;
            __syncthreads();
            scn[tid] = v + add;
            __syncthreads();
        }
        {
            int excl = scn[tid] - csum;
            for (int k = 0; k < chunk && k < 4; ++k) {
                int s = sbase + k;
                if (s < S) cum[s + 1] = excl + local[k];
            }
            if (tid == 0) cum[0] = 0;
        }
        __syncthreads();
        const int total = cum[S];
        for (int m = tid; m < M; m += 256) {
            int mm = m;
            if (mm >= total) mm = (total > 0) ? (total - 1) : 0;  // jnp.repeat pad
            int lo = 0, hi = S - 1;
            while (lo < hi) {
                int mid = (lo + hi) >> 1;
                if (cum[mid + 1] <= mm) lo = mid + 1; else hi = mid;
            }
            scatter[m] = lo;
        }
    }
}

// 1 block x 256 threads. Sets flag; if identity mask, returns immediately.
// Otherwise builds the nonzero compaction (rcidx/starts/ends) — rare path.
__global__ void build_kernel(const int* __restrict__ counts,
                             const int* __restrict__ mask2d,
                             int* __restrict__ rcidx,
                             float* __restrict__ starts,
                             float* __restrict__ ends,
                             int* __restrict__ flag,
                             int N, int P) {
    const int tid = threadIdx.x;
    __shared__ int scan[256];

    scan[tid] = (tid < NCNT) ? counts[tid] : 0;
    __syncthreads();
    for (int st = 128; st > 0; st >>= 1) {
        if (tid < st) scan[tid] += scan[tid + st];
        __syncthreads();
    }
    const int K_all = scan[0];
    const int f = (K_all == P && (P & 3) == 0 && N <= MAXN_TAB) ? 1 : 0;
    if (tid == 0) flag[0] = f;
    if (f) return;                 // uniform branch: all threads exit
    __syncthreads();

    // ---- general compaction (parallel scan over per-thread chunks) ----
    const int per = (P + 255) / 256;
    const int base = tid * per;
    int cnt = 0;
    for (int k = 0; k < per; ++k) {
        int j = base + k;
        if (j < P && mask2d[j] != 0) cnt++;
    }
    scan[tid] = cnt;
    __syncthreads();
    for (int d = 1; d < 256; d <<= 1) {
        int v = scan[tid];
        int add = (tid >= d) ? scan[tid - d] : 0;
        __syncthreads();
        scan[tid] = v + add;
        __syncthreads();
    }
    const int K = scan[255];
    int pos = scan[tid] - cnt;     // exclusive prefix

    const float fN = (float)N;
    for (int k = 0; k < per; ++k) {
        int j = base + k;
        if (j < P && mask2d[j] != 0) {
            int r = j / N;
            int c = j - r * N;
            rcidx[pos]  = j;
            starts[pos] = (float)r / fN;        // exact reference op
            ends[pos]   = (float)(c + 1) / fN;
            pos++;
        }
    }
    __syncthreads();
    for (int j = K + tid; j < P; j += 256) {    // nonzero(size=P) pads with index 0
        rcidx[j]  = 0;
        starts[j] = 0.0f;
        ends[j]   = 1.0f / fN;
    }
}

// One block per target row m. 256 threads. Per-block partials (no atomics).
__global__ __launch_bounds__(256)
void loss_kernel(const float* __restrict__ start_offset,
                 const float* __restrict__ end_offset,
                 const float* __restrict__ tgt_moments,
                 const int* __restrict__ scatter,
                 const float* __restrict__ iou2ds,
                 const int* __restrict__ rcidx,
                 const float* __restrict__ starts,
                 const float* __restrict__ ends,
                 double* __restrict__ psum,
                 int* __restrict__ pcnt,
                 const int* __restrict__ flag,
                 int P, int M, int N) {
    // XCD-aware mapping: the 4 consecutive m sharing one start_offset row land
    // on the same XCD (blocks dispatch round-robin across 8 XCDs by blockIdx).
    const int bid = blockIdx.x;
    const int m = ((M & 7) == 0) ? ((bid & 7) * (M >> 3) + (bid >> 3)) : bid;
    const int tid = threadIdx.x;
    const int s   = scatter[m];
    const int fp  = flag[0];

    const float* __restrict__ so_row  = start_offset + (size_t)s * P;
    const float* __restrict__ eo_row  = end_offset   + (size_t)s * P;
    const float* __restrict__ iou_row = iou2ds       + (size_t)m * P;
    const float tgt0 = tgt_moments[2 * m];
    const float tgt1 = tgt_moments[2 * m + 1];

    // dynamic LDS tables for the identity-compaction fast path (2*N floats)
    extern __shared__ float tabs[];
    float* st_tab = tabs;
    float* en_tab = tabs + N;
    if (fp) {
        const float fN = (float)N;
        for (int i = tid; i < N; i += 256) {
            st_tab[i] = (float)i / fN;          // bit-identical to reference
            en_tab[i] = (float)(i + 1) / fN;
        }
        __syncthreads();
    }

    double lsum = 0.0;
    int    lcnt = 0;

    // thread-local top-3 (sorted desc, stable)
    float v0 = -INFINITY, v1 = -INFINITY, v2 = -INFINITY;
    int   i0 = 0x7fffffff, i1 = 0x7fffffff, i2 = 0x7fffffff;

#define PROC(v, jj, so_, eo_, st_, en_)                                         \
    do {                                                                        \
        if (better(v, jj, v2, i2)) {                                            \
            if (better(v, jj, v1, i1)) {                                        \
                v2 = v1; i2 = i1;                                               \
                if (better(v, jj, v0, i0)) { v1 = v0; i1 = i0; v0 = v; i0 = jj; } \
                else                       { v1 = v;  i1 = jj; }                \
            } else { v2 = v; i2 = jj; }                                         \
        }                                                                       \
        if (v > IOU_THR) {                                                      \
            const float sot = tgt0 - (st_);                                     \
            const float eot = tgt1 - (en_);                                     \
            lsum += (double)(fabsf((so_) - sot) + fabsf((eo_) - eot));          \
            lcnt++;                                                             \
        }                                                                       \
    } while (0)

    if (fp) {
        const float4* __restrict__ iou4 = (const float4*)iou_row;
        const float4* __restrict__ so4  = (const float4*)so_row;
        const float4* __restrict__ eo4  = (const float4*)eo_row;
        const int P4 = P >> 2;
        for (int q = tid; q < P4; q += 256) {
            const float4 vi = iou4[q];
            const float4 vs = so4[q];
            const float4 ve = eo4[q];
            const int j = q << 2;
            int r = j / N;            // one div per 4-element group
            int c = j - r * N;
            PROC(vi.x, j + 0, vs.x, ve.x, st_tab[r], en_tab[c]);
            c++; if (c == N) { c = 0; r++; }
            PROC(vi.y, j + 1, vs.y, ve.y, st_tab[r], en_tab[c]);
            c++; if (c == N) { c = 0; r++; }
            PROC(vi.z, j + 2, vs.z, ve.z, st_tab[r], en_tab[c]);
            c++; if (c == N) { c = 0; r++; }
            PROC(vi.w, j + 3, vs.w, ve.w, st_tab[r], en_tab[c]);
        }
    } else {
        for (int j = tid; j < P; j += 256) {
            const int   idx = rcidx[j];
            const float v   = iou_row[idx];
            PROC(v, j, so_row[j], eo_row[j], starts[j], ends[j]);
        }
    }
#undef PROC

    // block-level stable top-3 merge reduction
    __shared__ float sv[256][3];
    __shared__ int   si[256][3];
    sv[tid][0] = v0; sv[tid][1] = v1; sv[tid][2] = v2;
    si[tid][0] = i0; si[tid][1] = i1; si[tid][2] = i2;
    __syncthreads();

    for (int str = 128; str > 0; str >>= 1) {
        if (tid < str) {
            float av0 = sv[tid][0], av1 = sv[tid][1], av2 = sv[tid][2];
            int   ai0 = si[tid][0], ai1 = si[tid][1], ai2 = si[tid][2];
            float bv0 = sv[tid + str][0], bv1 = sv[tid + str][1], bv2 = sv[tid + str][2];
            int   bi0 = si[tid + str][0], bi1 = si[tid + str][1], bi2 = si[tid + str][2];

            bool t0 = better(av0, ai0, bv0, bi0);
            float ov0 = t0 ? av0 : bv0;  int oi0 = t0 ? ai0 : bi0;
            float ahv = t0 ? av1 : av0;  int ahi = t0 ? ai1 : ai0;
            float a2v = t0 ? av2 : av1;  int a2i = t0 ? ai2 : ai1;
            float bhv = t0 ? bv0 : bv1;  int bhi = t0 ? bi0 : bi1;
            float b2v = t0 ? bv1 : bv2;  int b2i = t0 ? bi1 : bi2;

            bool t1 = better(ahv, ahi, bhv, bhi);
            float ov1 = t1 ? ahv : bhv;  int oi1 = t1 ? ahi : bhi;
            float cav = t1 ? a2v : ahv;  int cai = t1 ? a2i : ahi;
            float cbv = t1 ? bhv : b2v;  int cbi = t1 ? bhi : b2i;

            bool t2 = better(cav, cai, cbv, cbi);
            float ov2 = t2 ? cav : cbv;  int oi2 = t2 ? cai : cbi;

            sv[tid][0] = ov0; sv[tid][1] = ov1; sv[tid][2] = ov2;
            si[tid][0] = oi0; si[tid][1] = oi1; si[tid][2] = oi2;
        }
        __syncthreads();
    }

    // top-3 entries not already counted by (iou > 0.5)
    if (tid < TOPK_N) {
        const float v = sv[0][tid];
        const int   j = si[0][tid];
        if (j != 0x7fffffff && !(v > IOU_THR)) {
            float stj, enj;
            if (fp) {
                int r = j / N, c = j - r * N;
                stj = st_tab[r]; enj = en_tab[c];
            } else {
                stj = starts[j]; enj = ends[j];
            }
            const float sot = tgt0 - stj;
            const float eot = tgt1 - enj;
            lsum += (double)(fabsf(so_row[j] - sot) + fabsf(eo_row[j] - eot));
            lcnt++;
        }
    }

    // block sum reduction -> per-block partials (no global atomics)
    __shared__ double dsum[256];
    __shared__ int    dcnt[256];
    dsum[tid] = lsum; dcnt[tid] = lcnt;
    __syncthreads();
    for (int str = 128; str > 0; str >>= 1) {
        if (tid < str) { dsum[tid] += dsum[tid + str]; dcnt[tid] += dcnt[tid + str]; }
        __syncthreads();
    }
    if (tid == 0) {
        psum[bid] = dsum[0];
        pcnt[bid] = dcnt[0];
    }
}

__global__ void finalize_kernel(const double* __restrict__ psum,
                                const int* __restrict__ pcnt,
                                int M, float* __restrict__ out) {
    __shared__ double sd[256];
    __shared__ int    sc[256];
    const int tid = threadIdx.x;
    double a = 0.0;
    int    c = 0;
    for (int i = tid; i < M; i += 256) { a += psum[i]; c += pcnt[i]; }
    sd[tid] = a; sc[tid] = c;
    __syncthreads();
    for (int str = 128; str > 0; str >>= 1) {
        if (tid < str) { sd[tid] += sd[tid + str]; sc[tid] += sc[tid + str]; }
        __syncthreads();
    }
    if (tid == 0) out[0] = (float)(sd[0] / (double)sc[0]);
}

extern "C" void kernel_launch(void* const* d_in, const int* in_sizes, int n_in,
                              void* d_out, int out_size, void* d_ws, size_t ws_size,
                              hipStream_t stream) {
    const float* start_offset = (const float*)d_in[0];
    const float* end_offset   = (const float*)d_in[1];
    const float* tgt_moments  = (const float*)d_in[2];
    const int*   num_targets  = (const int*)d_in[3];
    const float* iou2ds       = (const float*)d_in[4];
    const int*   mask2d       = (const int*)d_in[5];   // bool pushed as int32

    const int S = in_sizes[3];
    const int M = in_sizes[2] / 2;
    const int P = in_sizes[0] / S;
    const int NN = in_sizes[5];
    int N = 1;
    while ((long long)N * N < (long long)NN) N++;

    // workspace layout (16B aligned blocks)
    char* ws = (char*)d_ws;
    size_t off = 0;
    int*    flag    = (int*)(ws + off);    off += 16;
    int*    counts  = (int*)(ws + off);    off += (NCNT * 4 + 15) & ~(size_t)15;
    int*    scatter = (int*)(ws + off);    off += ((size_t)M * 4 + 15) & ~(size_t)15;
    int*    rcidx   = (int*)(ws + off);    off += ((size_t)P * 4 + 15) & ~(size_t)15;
    float*  starts  = (float*)(ws + off);  off += ((size_t)P * 4 + 15) & ~(size_t)15;
    float*  ends    = (float*)(ws + off);  off += ((size_t)P * 4 + 15) & ~(size_t)15;
    double* psum    = (double*)(ws + off); off += ((size_t)M * 8 + 15) & ~(size_t)15;
    int*    pcnt    = (int*)(ws + off);    off += ((size_t)M * 4 + 15) & ~(size_t)15;

    const size_t tab_bytes = (size_t)2 * N * sizeof(float);

    prep_kernel<<<NCNT + 1, 256, 0, stream>>>(num_targets, mask2d, scatter, counts,
                                              S, M, P);
    build_kernel<<<1, 256, 0, stream>>>(counts, mask2d, rcidx, starts, ends, flag, N, P);
    loss_kernel<<<M, 256, tab_bytes, stream>>>(start_offset, end_offset, tgt_moments,
                                               scatter, iou2ds, rcidx, starts, ends,
                                               psum, pcnt, flag, P, M, N);
    finalize_kernel<<<1, 256, 0, stream>>>(psum, pcnt, M, (float*)d_out);
}

// Round 5
// 36.258 us; speedup vs baseline: 3.0823x; 1.1796x over previous
//
#include <hip/hip_runtime.h>
#include <math.h>

#define TOPK_N 3
#define IOU_THR 0.5f
#define NCNT 64           // counting blocks in prep_kernel
#define THREADS 512
#define NW (THREADS / 64)
#define SENT 0x7fffffff

__device__ __forceinline__ bool better(float va, int ia, float vb, int ib) {
    // lax.top_k ordering: higher value first; ties -> lower index first
    return (va > vb) || (va == vb && ia < ib);
}

// merge two desc-sorted stable top3 triples -> (a*, x*)
__device__ __forceinline__ void merge3(float& a0, float& a1, float& a2,
                                       int& x0, int& x1, int& x2,
                                       float b0, float b1, float b2,
                                       int y0, int y1, int y2) {
    bool t0 = better(a0, x0, b0, y0);
    float ov0 = t0 ? a0 : b0;  int oi0 = t0 ? x0 : y0;
    float ahv = t0 ? a1 : a0;  int ahi = t0 ? x1 : x0;
    float a2v = t0 ? a2 : a1;  int a2i = t0 ? x2 : x1;
    float bhv = t0 ? b0 : b1;  int bhi = t0 ? y0 : y1;
    float b2v = t0 ? b1 : b2;  int b2i = t0 ? y1 : y2;
    bool t1 = better(ahv, ahi, bhv, bhi);
    float ov1 = t1 ? ahv : bhv; int oi1 = t1 ? ahi : bhi;
    float cav = t1 ? a2v : ahv; int cai = t1 ? a2i : ahi;
    float cbv = t1 ? bhv : b2v; int cbi = t1 ? bhi : b2i;
    bool t2 = better(cav, cai, cbv, cbi);
    a0 = ov0; a1 = ov1; a2 = t2 ? cav : cbv;
    x0 = oi0; x1 = oi1; x2 = t2 ? cai : cbi;
}

// 65 blocks x 256 threads.
// Blocks 0..63: partial nonzero counts of mask2d (coalesced int4) -> counts[bid].
// Block 64: cumsum of num_targets + scatter_m2s (jnp.repeat semantics).
__global__ void prep_kernel(const int* __restrict__ num_targets,
                            const int* __restrict__ mask2d,
                            int* __restrict__ scatter,
                            int* __restrict__ counts,
                            int S, int M, int P) {
    const int bid = blockIdx.x;
    const int tid = threadIdx.x;

    if (bid < NCNT) {
        const int P4 = P >> 2;
        const int4* __restrict__ m4 = (const int4*)mask2d;
        int c = 0;
        for (int q = bid * 256 + tid; q < P4; q += NCNT * 256) {
            const int4 v = m4[q];
            c += (v.x != 0) + (v.y != 0) + (v.z != 0) + (v.w != 0);
        }
        if (bid == 0) {                       // scalar tail if P % 4 != 0
            for (int j = (P4 << 2) + tid; j < P; j += 256)
                c += (mask2d[j] != 0);
        }
        __shared__ int red[256];
        red[tid] = c;
        __syncthreads();
        for (int st = 128; st > 0; st >>= 1) {
            if (tid < st) red[tid] += red[tid + st];
            __syncthreads();
        }
        if (tid == 0) counts[bid] = red[0];
    } else {
        // ---- cumsum of num_targets (parallel) + scatter ----
        __shared__ int cum[1025];   // supports S <= 1024
        __shared__ int scn[256];
        const int chunk = (S + 255) / 256;   // <= 4 for S <= 1024
        const int sbase = tid * chunk;
        int local[4];
        int csum = 0;
        for (int k = 0; k < chunk && k < 4; ++k) {
            int s = sbase + k;
            int v = (s < S) ? num_targets[s] : 0;
            csum += v;
            local[k] = csum;                 // inclusive within chunk
        }
        scn[tid] = csum;
        __syncthreads();
        for (int d = 1; d < 256; d <<= 1) {  // Hillis-Steele inclusive scan
            int v = scn[tid];
            int add = (tid >= d) ? scn[tid - d] : 0;
            __syncthreads();
            scn[tid] = v + add;
            __syncthreads();
        }
        {
            int excl = scn[tid] - csum;
            for (int k = 0; k < chunk && k < 4; ++k) {
                int s = sbase + k;
                if (s < S) cum[s + 1] = excl + local[k];
            }
            if (tid == 0) cum[0] = 0;
        }
        __syncthreads();
        const int total = cum[S];
        for (int m = tid; m < M; m += 256) {
            int mm = m;
            if (mm >= total) mm = (total > 0) ? (total - 1) : 0;  // jnp.repeat pad
            int lo = 0, hi = S - 1;
            while (lo < hi) {
                int mid = (lo + hi) >> 1;
                if (cum[mid + 1] <= mm) lo = mid + 1; else hi = mid;
            }
            scatter[m] = lo;
        }
    }
}

// 1 block x 256 threads. Sets flag; if identity mask + pow2 N, returns.
// Otherwise builds the nonzero compaction (rcidx/starts/ends) — rare path.
__global__ void build_kernel(const int* __restrict__ counts,
                             const int* __restrict__ mask2d,
                             int* __restrict__ rcidx,
                             float* __restrict__ starts,
                             float* __restrict__ ends,
                             int* __restrict__ flag,
                             int N, int P) {
    const int tid = threadIdx.x;
    __shared__ int scan[256];

    scan[tid] = (tid < NCNT) ? counts[tid] : 0;
    __syncthreads();
    for (int st = 128; st > 0; st >>= 1) {
        if (tid < st) scan[tid] += scan[tid + st];
        __syncthreads();
    }
    const int K_all = scan[0];
    const int f = (K_all == P && (P & 3) == 0 && (N & (N - 1)) == 0) ? 1 : 0;
    if (tid == 0) flag[0] = f;
    if (f) return;                 // uniform branch: all threads exit
    __syncthreads();

    // ---- general compaction (parallel scan over per-thread chunks) ----
    const int per = (P + 255) / 256;
    const int base = tid * per;
    int cnt = 0;
    for (int k = 0; k < per; ++k) {
        int j = base + k;
        if (j < P && mask2d[j] != 0) cnt++;
    }
    scan[tid] = cnt;
    __syncthreads();
    for (int d = 1; d < 256; d <<= 1) {
        int v = scan[tid];
        int add = (tid >= d) ? scan[tid - d] : 0;
        __syncthreads();
        scan[tid] = v + add;
        __syncthreads();
    }
    const int K = scan[255];
    int pos = scan[tid] - cnt;     // exclusive prefix

    const float fN = (float)N;
    for (int k = 0; k < per; ++k) {
        int j = base + k;
        if (j < P && mask2d[j] != 0) {
            int r = j / N;
            int c = j - r * N;
            rcidx[pos]  = j;
            starts[pos] = (float)r / fN;        // exact reference op
            ends[pos]   = (float)(c + 1) / fN;
            pos++;
        }
    }
    __syncthreads();
    for (int j = K + tid; j < P; j += 256) {    // nonzero(size=P) pads with index 0
        rcidx[j]  = 0;
        starts[j] = 0.0f;
        ends[j]   = 1.0f / fN;
    }
}

// One block (512 threads) per target row m. Per-block partials (no atomics).
__global__ __launch_bounds__(THREADS, 8)
void loss_kernel(const float* __restrict__ start_offset,
                 const float* __restrict__ end_offset,
                 const float* __restrict__ tgt_moments,
                 const int* __restrict__ scatter,
                 const float* __restrict__ iou2ds,
                 const int* __restrict__ rcidx,
                 const float* __restrict__ starts,
                 const float* __restrict__ ends,
                 double* __restrict__ psum,
                 int* __restrict__ pcnt,
                 const int* __restrict__ flag,
                 int P, int M, int N) {
    // XCD-aware mapping: the 4 consecutive m sharing one start_offset row land
    // on the same XCD (blocks dispatch round-robin across 8 XCDs by blockIdx).
    const int bid = blockIdx.x;
    const int m = ((M & 7) == 0) ? ((bid & 7) * (M >> 3) + (bid >> 3)) : bid;
    const int tid = threadIdx.x;
    const int s   = scatter[m];
    const int fp  = flag[0];

    const float* __restrict__ so_row  = start_offset + (size_t)s * P;
    const float* __restrict__ eo_row  = end_offset   + (size_t)s * P;
    const float* __restrict__ iou_row = iou2ds       + (size_t)m * P;
    const float tgt0 = tgt_moments[2 * m];
    const float tgt1 = tgt_moments[2 * m + 1];

    const int   lgN  = 31 - __clz(N);       // valid when fp (N pow2)
    const float invN = 1.0f / (float)N;     // exact for pow2 N

    float lsum = 0.0f;
    int   lcnt = 0;

    // thread-local top-3 (sorted desc). Within a thread j strictly increases,
    // so STRICT > compares realize lax.top_k's lowest-index-on-tie semantics.
    float v0 = -INFINITY, v1 = -INFINITY, v2 = -INFINITY;
    int   i0 = SENT, i1 = SENT, i2 = SENT;

#define PROC(v, jj, so_, eo_, st_, en_)                                     \
    do {                                                                    \
        const bool b0 = (v) > v0;                                           \
        const bool b1 = (v) > v1;                                           \
        const bool b2 = (v) > v2;                                           \
        v2 = b1 ? v1 : (b2 ? (v) : v2);  i2 = b1 ? i1 : (b2 ? (jj) : i2);   \
        v1 = b0 ? v0 : (b1 ? (v) : v1);  i1 = b0 ? i0 : (b1 ? (jj) : i1);   \
        v0 = b0 ? (v) : v0;              i0 = b0 ? (jj) : i0;               \
        const bool sel = (v) > IOU_THR;                                     \
        const float l_ = fabsf((so_) - (tgt0 - (st_))) +                    \
                         fabsf((eo_) - (tgt1 - (en_)));                     \
        lsum += sel ? l_ : 0.0f;                                            \
        lcnt += sel ? 1 : 0;                                                \
    } while (0)

    if (fp) {
        const float4* __restrict__ iou4 = (const float4*)iou_row;
        const float4* __restrict__ so4  = (const float4*)so_row;
        const float4* __restrict__ eo4  = (const float4*)eo_row;
        const int P4 = P >> 2;
        for (int q = tid; q < P4; q += THREADS) {
            const float4 vi = iou4[q];
            const float4 vs = so4[q];
            const float4 ve = eo4[q];
            const int j  = q << 2;
            const int r  = j >> lgN;        // pow2 N: exact, no wrap within group
            const int c0 = j & (N - 1);     // (j%4==0, N>=4) -> c0..c0+3 same row
            const float st = (float)r * invN;            // == r/N exactly (pow2)
            const float e0 = (float)(c0 + 1) * invN;     // == (c+1)/N exactly
            const float e1 = (float)(c0 + 2) * invN;
            const float e2 = (float)(c0 + 3) * invN;
            const float e3 = (float)(c0 + 4) * invN;
            PROC(vi.x, j + 0, vs.x, ve.x, st, e0);
            PROC(vi.y, j + 1, vs.y, ve.y, st, e1);
            PROC(vi.z, j + 2, vs.z, ve.z, st, e2);
            PROC(vi.w, j + 3, vs.w, ve.w, st, e3);
        }
    } else {
        for (int j = tid; j < P; j += THREADS) {
            const int   idx = rcidx[j];
            const float v   = iou_row[idx];
            PROC(v, j, so_row[j], eo_row[j], starts[j], ends[j]);
        }
    }
#undef PROC

    // ---- wave-level reductions (shuffle butterflies, no LDS) ----
    for (int d = 1; d < 64; d <<= 1) {
        float bv0 = __shfl_xor(v0, d), bv1 = __shfl_xor(v1, d), bv2 = __shfl_xor(v2, d);
        int   by0 = __shfl_xor(i0, d), by1 = __shfl_xor(i1, d), by2 = __shfl_xor(i2, d);
        merge3(v0, v1, v2, i0, i1, i2, bv0, bv1, bv2, by0, by1, by2);
    }
    double dsum = (double)lsum;
    for (int d = 1; d < 64; d <<= 1) dsum += __shfl_xor(dsum, d);
    for (int d = 1; d < 64; d <<= 1) lcnt += __shfl_xor(lcnt, d);

    // ---- cross-wave merge via tiny LDS ----
    __shared__ float  wv[NW][3];
    __shared__ int    wi[NW][3];
    __shared__ double wsum[NW];
    __shared__ int    wcnt[NW];
    const int wid  = tid >> 6;
    const int lane = tid & 63;
    if (lane == 0) {
        wv[wid][0] = v0; wv[wid][1] = v1; wv[wid][2] = v2;
        wi[wid][0] = i0; wi[wid][1] = i1; wi[wid][2] = i2;
        wsum[wid] = dsum; wcnt[wid] = lcnt;
    }
    __syncthreads();

    if (tid == 0) {
        float a0 = wv[0][0], a1 = wv[0][1], a2 = wv[0][2];
        int   x0 = wi[0][0], x1 = wi[0][1], x2 = wi[0][2];
        double S = wsum[0];
        int    C = wcnt[0];
        for (int w = 1; w < NW; ++w) {
            merge3(a0, a1, a2, x0, x1, x2,
                   wv[w][0], wv[w][1], wv[w][2],
                   wi[w][0], wi[w][1], wi[w][2]);
            S += wsum[w];
            C += wcnt[w];
        }
        // top-3 entries not already counted by (iou > 0.5)
#define ADDTOP(vk, jk)                                                      \
        do {                                                                \
            if ((jk) != SENT && !((vk) > IOU_THR)) {                        \
                float st_, en_;                                             \
                if (fp) {                                                   \
                    int r_ = (jk) >> lgN, c_ = (jk) & (N - 1);              \
                    st_ = (float)r_ * invN; en_ = (float)(c_ + 1) * invN;   \
                } else { st_ = starts[jk]; en_ = ends[jk]; }                \
                S += (double)(fabsf(so_row[jk] - (tgt0 - st_)) +            \
                              fabsf(eo_row[jk] - (tgt1 - en_)));            \
                C += 1;                                                     \
            }                                                               \
        } while (0)
        ADDTOP(a0, x0);
        ADDTOP(a1, x1);
        ADDTOP(a2, x2);
#undef ADDTOP
        psum[bid] = S;
        pcnt[bid] = C;
    }
}

__global__ void finalize_kernel(const double* __restrict__ psum,
                                const int* __restrict__ pcnt,
                                int M, float* __restrict__ out) {
    __shared__ double sd[256];
    __shared__ int    sc[256];
    const int tid = threadIdx.x;
    double a = 0.0;
    int    c = 0;
    for (int i = tid; i < M; i += 256) { a += psum[i]; c += pcnt[i]; }
    sd[tid] = a; sc[tid] = c;
    __syncthreads();
    for (int str = 128; str > 0; str >>= 1) {
        if (tid < str) { sd[tid] += sd[tid + str]; sc[tid] += sc[tid + str]; }
        __syncthreads();
    }
    if (tid == 0) out[0] = (float)(sd[0] / (double)sc[0]);
}

extern "C" void kernel_launch(void* const* d_in, const int* in_sizes, int n_in,
                              void* d_out, int out_size, void* d_ws, size_t ws_size,
                              hipStream_t stream) {
    const float* start_offset = (const float*)d_in[0];
    const float* end_offset   = (const float*)d_in[1];
    const float* tgt_moments  = (const float*)d_in[2];
    const int*   num_targets  = (const int*)d_in[3];
    const float* iou2ds       = (const float*)d_in[4];
    const int*   mask2d       = (const int*)d_in[5];   // bool pushed as int32

    const int S = in_sizes[3];
    const int M = in_sizes[2] / 2;
    const int P = in_sizes[0] / S;
    const int NN = in_sizes[5];
    int N = 1;
    while ((long long)N * N < (long long)NN) N++;

    // workspace layout (16B aligned blocks)
    char* ws = (char*)d_ws;
    size_t off = 0;
    int*    flag    = (int*)(ws + off);    off += 16;
    int*    counts  = (int*)(ws + off);    off += (NCNT * 4 + 15) & ~(size_t)15;
    int*    scatter = (int*)(ws + off);    off += ((size_t)M * 4 + 15) & ~(size_t)15;
    int*    rcidx   = (int*)(ws + off);    off += ((size_t)P * 4 + 15) & ~(size_t)15;
    float*  starts  = (float*)(ws + off);  off += ((size_t)P * 4 + 15) & ~(size_t)15;
    float*  ends    = (float*)(ws + off);  off += ((size_t)P * 4 + 15) & ~(size_t)15;
    double* psum    = (double*)(ws + off); off += ((size_t)M * 8 + 15) & ~(size_t)15;
    int*    pcnt    = (int*)(ws + off);    off += ((size_t)M * 4 + 15) & ~(size_t)15;

    prep_kernel<<<NCNT + 1, 256, 0, stream>>>(num_targets, mask2d, scatter, counts,
                                              S, M, P);
    build_kernel<<<1, 256, 0, stream>>>(counts, mask2d, rcidx, starts, ends, flag, N, P);
    loss_kernel<<<M, THREADS, 0, stream>>>(start_offset, end_offset, tgt_moments,
                                           scatter, iou2ds, rcidx, starts, ends,
                                           psum, pcnt, flag, P, M, N);
    finalize_kernel<<<1, 256, 0, stream>>>(psum, pcnt, M, (float*)d_out);
}

// Round 6
// 34.547 us; speedup vs baseline: 3.2350x; 1.0495x over previous
//
#include <hip/hip_runtime.h>
#include <math.h>

#define TOPK_N 3
#define IOU_THR 0.5f
#define NCNT 8            // counting blocks in prep_kernel
#define THREADS 512
#define NW (THREADS / 64)
#define SENT 0x7fffffff

__device__ __forceinline__ bool better(float va, int ia, float vb, int ib) {
    // lax.top_k ordering: higher value first; ties -> lower index first
    return (va > vb) || (va == vb && ia < ib);
}

// merge two desc-sorted stable top3 triples -> (a*, x*)
__device__ __forceinline__ void merge3(float& a0, float& a1, float& a2,
                                       int& x0, int& x1, int& x2,
                                       float b0, float b1, float b2,
                                       int y0, int y1, int y2) {
    bool t0 = better(a0, x0, b0, y0);
    float ov0 = t0 ? a0 : b0;  int oi0 = t0 ? x0 : y0;
    float ahv = t0 ? a1 : a0;  int ahi = t0 ? x1 : x0;
    float a2v = t0 ? a2 : a1;  int a2i = t0 ? x2 : x1;
    float bhv = t0 ? b0 : b1;  int bhi = t0 ? y0 : y1;
    float b2v = t0 ? b1 : b2;  int b2i = t0 ? y1 : y2;
    bool t1 = better(ahv, ahi, bhv, bhi);
    float ov1 = t1 ? ahv : bhv; int oi1 = t1 ? ahi : bhi;
    float cav = t1 ? a2v : ahv; int cai = t1 ? a2i : ahi;
    float cbv = t1 ? bhv : b2v; int cbi = t1 ? bhi : b2i;
    bool t2 = better(cav, cai, cbv, cbi);
    a0 = ov0; a1 = ov1; a2 = t2 ? cav : cbv;
    x0 = oi0; x1 = oi1; x2 = t2 ? cai : cbi;
}

// NCNT+1 blocks x 256 threads.
// Blocks 0..NCNT-1: partial nonzero counts of mask2d (coalesced int4).
// Block NCNT: cumsum of num_targets + scatter_m2s (jnp.repeat semantics).
__global__ void prep_kernel(const int* __restrict__ num_targets,
                            const int* __restrict__ mask2d,
                            int* __restrict__ scatter,
                            int* __restrict__ counts,
                            int S, int M, int P) {
    const int bid = blockIdx.x;
    const int tid = threadIdx.x;

    if (bid < NCNT) {
        const int P4 = P >> 2;
        const int4* __restrict__ m4 = (const int4*)mask2d;
        int c = 0;
        for (int q = bid * 256 + tid; q < P4; q += NCNT * 256) {
            const int4 v = m4[q];
            c += (v.x != 0) + (v.y != 0) + (v.z != 0) + (v.w != 0);
        }
        if (bid == 0) {                       // scalar tail if P % 4 != 0
            for (int j = (P4 << 2) + tid; j < P; j += 256)
                c += (mask2d[j] != 0);
        }
        __shared__ int red[256];
        red[tid] = c;
        __syncthreads();
        for (int st = 128; st > 0; st >>= 1) {
            if (tid < st) red[tid] += red[tid + st];
            __syncthreads();
        }
        if (tid == 0) counts[bid] = red[0];
    } else {
        // ---- cumsum of num_targets (parallel) + scatter ----
        __shared__ int cum[1025];   // supports S <= 1024
        __shared__ int scn[256];
        const int chunk = (S + 255) / 256;   // <= 4 for S <= 1024
        const int sbase = tid * chunk;
        int local[4];
        int csum = 0;
        for (int k = 0; k < chunk && k < 4; ++k) {
            int s = sbase + k;
            int v = (s < S) ? num_targets[s] : 0;
            csum += v;
            local[k] = csum;                 // inclusive within chunk
        }
        scn[tid] = csum;
        __syncthreads();
        for (int d = 1; d < 256; d <<= 1) {  // Hillis-Steele inclusive scan
            int v = scn[tid];
            int add = (tid >= d) ? scn[tid - d] : 0;
            __syncthreads();
            scn[tid] = v + add;
            __syncthreads();
        }
        {
            int excl = scn[tid] - csum;
            for (int k = 0; k < chunk && k < 4; ++k) {
                int s = sbase + k;
                if (s < S) cum[s + 1] = excl + local[k];
            }
            if (tid == 0) cum[0] = 0;
        }
        __syncthreads();
        const int total = cum[S];
        for (int m = tid; m < M; m += 256) {
            int mm = m;
            if (mm >= total) mm = (total > 0) ? (total - 1) : 0;  // jnp.repeat pad
            int lo = 0, hi = S - 1;
            while (lo < hi) {
                int mid = (lo + hi) >> 1;
                if (cum[mid + 1] <= mm) lo = mid + 1; else hi = mid;
            }
            scatter[m] = lo;
        }
    }
}

// 1 block x 256 threads. Sets flag; if identity mask + pow2 N, returns.
// Otherwise builds the nonzero compaction (rcidx/starts/ends) — rare path.
__global__ void build_kernel(const int* __restrict__ counts,
                             const int* __restrict__ mask2d,
                             int* __restrict__ rcidx,
                             float* __restrict__ starts,
                             float* __restrict__ ends,
                             int* __restrict__ flag,
                             int N, int P) {
    const int tid = threadIdx.x;
    __shared__ int scan[256];

    scan[tid] = (tid < NCNT) ? counts[tid] : 0;
    __syncthreads();
    for (int st = 128; st > 0; st >>= 1) {
        if (tid < st) scan[tid] += scan[tid + st];
        __syncthreads();
    }
    const int K_all = scan[0];
    const int f = (K_all == P && (P & 3) == 0 && (N & (N - 1)) == 0 && N >= 4) ? 1 : 0;
    if (tid == 0) flag[0] = f;
    if (f) return;                 // uniform branch: all threads exit
    __syncthreads();

    // ---- general compaction (parallel scan over per-thread chunks) ----
    const int per = (P + 255) / 256;
    const int base = tid * per;
    int cnt = 0;
    for (int k = 0; k < per; ++k) {
        int j = base + k;
        if (j < P && mask2d[j] != 0) cnt++;
    }
    scan[tid] = cnt;
    __syncthreads();
    for (int d = 1; d < 256; d <<= 1) {
        int v = scan[tid];
        int add = (tid >= d) ? scan[tid - d] : 0;
        __syncthreads();
        scan[tid] = v + add;
        __syncthreads();
    }
    const int K = scan[255];
    int pos = scan[tid] - cnt;     // exclusive prefix

    const float fN = (float)N;
    for (int k = 0; k < per; ++k) {
        int j = base + k;
        if (j < P && mask2d[j] != 0) {
            int r = j / N;
            int c = j - r * N;
            rcidx[pos]  = j;
            starts[pos] = (float)r / fN;        // exact reference op
            ends[pos]   = (float)(c + 1) / fN;
            pos++;
        }
    }
    __syncthreads();
    for (int j = K + tid; j < P; j += 256) {    // nonzero(size=P) pads with index 0
        rcidx[j]  = 0;
        starts[j] = 0.0f;
        ends[j]   = 1.0f / fN;
    }
}

// One block (512 threads) per target row m. Per-block partials (no atomics).
__global__ __launch_bounds__(THREADS, 8)
void loss_kernel(const float* __restrict__ start_offset,
                 const float* __restrict__ end_offset,
                 const float* __restrict__ tgt_moments,
                 const int* __restrict__ scatter,
                 const float* __restrict__ iou2ds,
                 const int* __restrict__ rcidx,
                 const float* __restrict__ starts,
                 const float* __restrict__ ends,
                 double* __restrict__ psum,
                 int* __restrict__ pcnt,
                 const int* __restrict__ flag,
                 int P, int M, int N) {
    // XCD-aware mapping: the 4 consecutive m sharing one start_offset row land
    // on the same XCD (blocks dispatch round-robin across 8 XCDs by blockIdx).
    const int bid = blockIdx.x;
    const int m = ((M & 7) == 0) ? ((bid & 7) * (M >> 3) + (bid >> 3)) : bid;
    const int tid = threadIdx.x;
    const int s   = scatter[m];
    const int fp  = flag[0];

    const float* __restrict__ so_row  = start_offset + (size_t)s * P;
    const float* __restrict__ eo_row  = end_offset   + (size_t)s * P;
    const float* __restrict__ iou_row = iou2ds       + (size_t)m * P;
    const float tgt0 = tgt_moments[2 * m];
    const float tgt1 = tgt_moments[2 * m + 1];

    const int   lgN  = 31 - __clz(N);       // valid when fp (N pow2)
    const float invN = 1.0f / (float)N;     // exact for pow2 N

    float lsum = 0.0f;
    int   lcnt = 0;

    // thread-local top-3 (sorted desc). Within a thread j strictly increases,
    // so STRICT > compares realize lax.top_k's lowest-index-on-tie semantics.
    float v0 = -INFINITY, v1 = -INFINITY, v2 = -INFINITY;
    int   i0 = SENT, i1 = SENT, i2 = SENT;

#define PROC(v, jj, so_, eo_, A_, B_)                                       \
    do {                                                                    \
        const bool b0 = (v) > v0;                                           \
        const bool b1 = (v) > v1;                                           \
        const bool b2 = (v) > v2;                                           \
        v2 = b1 ? v1 : (b2 ? (v) : v2);  i2 = b1 ? i1 : (b2 ? (jj) : i2);   \
        v1 = b0 ? v0 : (b1 ? (v) : v1);  i1 = b0 ? i0 : (b1 ? (jj) : i1);   \
        v0 = b0 ? (v) : v0;              i0 = b0 ? (jj) : i0;               \
        const bool sel = (v) > IOU_THR;                                     \
        const float l_ = fabsf((so_) - (A_)) + fabsf((eo_) - (B_));         \
        lsum += sel ? l_ : 0.0f;                                            \
        lcnt += sel ? 1 : 0;                                                \
    } while (0)

    // process one float4 triple at float4-index q (row-constant A hoisted)
#define PROC4(vi, vs, ve, q)                                                \
    do {                                                                    \
        const int j_  = (q) << 2;                                           \
        const int r_  = j_ >> lgN;                                          \
        const int c_  = j_ & (N - 1);                                       \
        const float A_  = tgt0 - (float)r_ * invN;   /* same row for 4 */   \
        const float en0 = (float)(c_ + 1) * invN;    /* exact pow2 scale */ \
        PROC((vi).x, j_ + 0, (vs).x, (ve).x, A_, tgt1 - en0);               \
        PROC((vi).y, j_ + 1, (vs).y, (ve).y, A_, tgt1 - (en0 + invN));      \
        PROC((vi).z, j_ + 2, (vs).z, (ve).z, A_, tgt1 - (en0 + 2.0f*invN)); \
        PROC((vi).w, j_ + 3, (vs).w, (ve).w, A_, tgt1 - (en0 + 3.0f*invN)); \
    } while (0)

    if (fp && (P & (8 * THREADS - 1)) == 0) {
        // batched fast path: 8 elements (two float4 slabs) per iteration ->
        // 6 independent dwordx4 in flight per wave per iteration (MLP 2x).
        const float4* __restrict__ iou4 = (const float4*)iou_row;
        const float4* __restrict__ so4  = (const float4*)so_row;
        const float4* __restrict__ eo4  = (const float4*)eo_row;
        const int ITERS = P >> (2 + 1 + 9);   // P / (8*THREADS) ... THREADS=512
        int qA = tid;                          // float4 index, slab A
        for (int it = 0; it < ITERS; ++it) {
            const int qB = qA + THREADS;
            const float4 iA = iou4[qA]; const float4 iB = iou4[qB];
            const float4 sA = so4[qA];  const float4 sB = so4[qB];
            const float4 eA = eo4[qA];  const float4 eB = eo4[qB];
            PROC4(iA, sA, eA, qA);
            PROC4(iB, sB, eB, qB);
            qA += 2 * THREADS;
        }
    } else if (fp) {
        const float4* __restrict__ iou4 = (const float4*)iou_row;
        const float4* __restrict__ so4  = (const float4*)so_row;
        const float4* __restrict__ eo4  = (const float4*)eo_row;
        const int P4 = P >> 2;
        for (int q = tid; q < P4; q += THREADS) {
            const float4 vi = iou4[q];
            const float4 vs = so4[q];
            const float4 ve = eo4[q];
            PROC4(vi, vs, ve, q);
        }
    } else {
        for (int j = tid; j < P; j += THREADS) {
            const int   idx = rcidx[j];
            const float v   = iou_row[idx];
            const float A_  = tgt0 - starts[j];
            const float B_  = tgt1 - ends[j];
            PROC(v, j, so_row[j], eo_row[j], A_, B_);
        }
    }
#undef PROC4
#undef PROC

    // ---- wave-level reductions (shuffle butterflies, no LDS) ----
    for (int d = 1; d < 64; d <<= 1) {
        float bv0 = __shfl_xor(v0, d), bv1 = __shfl_xor(v1, d), bv2 = __shfl_xor(v2, d);
        int   by0 = __shfl_xor(i0, d), by1 = __shfl_xor(i1, d), by2 = __shfl_xor(i2, d);
        merge3(v0, v1, v2, i0, i1, i2, bv0, bv1, bv2, by0, by1, by2);
    }
    double dsum = (double)lsum;
    for (int d = 1; d < 64; d <<= 1) dsum += __shfl_xor(dsum, d);
    for (int d = 1; d < 64; d <<= 1) lcnt += __shfl_xor(lcnt, d);

    // ---- cross-wave merge via tiny LDS ----
    __shared__ float  wv[NW][3];
    __shared__ int    wi[NW][3];
    __shared__ double wsum[NW];
    __shared__ int    wcnt[NW];
    const int wid  = tid >> 6;
    const int lane = tid & 63;
    if (lane == 0) {
        wv[wid][0] = v0; wv[wid][1] = v1; wv[wid][2] = v2;
        wi[wid][0] = i0; wi[wid][1] = i1; wi[wid][2] = i2;
        wsum[wid] = dsum; wcnt[wid] = lcnt;
    }
    __syncthreads();

    if (tid == 0) {
        float a0 = wv[0][0], a1 = wv[0][1], a2 = wv[0][2];
        int   x0 = wi[0][0], x1 = wi[0][1], x2 = wi[0][2];
        double S = wsum[0];
        int    C = wcnt[0];
        for (int w = 1; w < NW; ++w) {
            merge3(a0, a1, a2, x0, x1, x2,
                   wv[w][0], wv[w][1], wv[w][2],
                   wi[w][0], wi[w][1], wi[w][2]);
            S += wsum[w];
            C += wcnt[w];
        }
        // top-3 entries not already counted by (iou > 0.5)
#define ADDTOP(vk, jk)                                                      \
        do {                                                                \
            if ((jk) != SENT && !((vk) > IOU_THR)) {                        \
                float st_, en_;                                             \
                if (fp) {                                                   \
                    int r_ = (jk) >> lgN, c_ = (jk) & (N - 1);              \
                    st_ = (float)r_ * invN; en_ = (float)(c_ + 1) * invN;   \
                } else { st_ = starts[jk]; en_ = ends[jk]; }                \
                S += (double)(fabsf(so_row[jk] - (tgt0 - st_)) +            \
                              fabsf(eo_row[jk] - (tgt1 - en_)));            \
                C += 1;                                                     \
            }                                                               \
        } while (0)
        ADDTOP(a0, x0);
        ADDTOP(a1, x1);
        ADDTOP(a2, x2);
#undef ADDTOP
        psum[bid] = S;
        pcnt[bid] = C;
    }
}

__global__ void finalize_kernel(const double* __restrict__ psum,
                                const int* __restrict__ pcnt,
                                int M, float* __restrict__ out) {
    __shared__ double sd[256];
    __shared__ int    sc[256];
    const int tid = threadIdx.x;
    double a = 0.0;
    int    c = 0;
    for (int i = tid; i < M; i += 256) { a += psum[i]; c += pcnt[i]; }
    sd[tid] = a; sc[tid] = c;
    __syncthreads();
    for (int str = 128; str > 0; str >>= 1) {
        if (tid < str) { sd[tid] += sd[tid + str]; sc[tid] += sc[tid + str]; }
        __syncthreads();
    }
    if (tid == 0) out[0] = (float)(sd[0] / (double)sc[0]);
}

extern "C" void kernel_launch(void* const* d_in, const int* in_sizes, int n_in,
                              void* d_out, int out_size, void* d_ws, size_t ws_size,
                              hipStream_t stream) {
    const float* start_offset = (const float*)d_in[0];
    const float* end_offset   = (const float*)d_in[1];
    const float* tgt_moments  = (const float*)d_in[2];
    const int*   num_targets  = (const int*)d_in[3];
    const float* iou2ds       = (const float*)d_in[4];
    const int*   mask2d       = (const int*)d_in[5];   // bool pushed as int32

    const int S = in_sizes[3];
    const int M = in_sizes[2] / 2;
    const int P = in_sizes[0] / S;
    const int NN = in_sizes[5];
    int N = 1;
    while ((long long)N * N < (long long)NN) N++;

    // workspace layout (16B aligned blocks)
    char* ws = (char*)d_ws;
    size_t off = 0;
    int*    flag    = (int*)(ws + off);    off += 16;
    int*    counts  = (int*)(ws + off);    off += (NCNT * 4 + 15) & ~(size_t)15;
    int*    scatter = (int*)(ws + off);    off += ((size_t)M * 4 + 15) & ~(size_t)15;
    int*    rcidx   = (int*)(ws + off);    off += ((size_t)P * 4 + 15) & ~(size_t)15;
    float*  starts  = (float*)(ws + off);  off += ((size_t)P * 4 + 15) & ~(size_t)15;
    float*  ends    = (float*)(ws + off);  off += ((size_t)P * 4 + 15) & ~(size_t)15;
    double* psum    = (double*)(ws + off); off += ((size_t)M * 8 + 15) & ~(size_t)15;
    int*    pcnt    = (int*)(ws + off);    off += ((size_t)M * 4 + 15) & ~(size_t)15;

    prep_kernel<<<NCNT + 1, 256, 0, stream>>>(num_targets, mask2d, scatter, counts,
                                              S, M, P);
    build_kernel<<<1, 256, 0, stream>>>(counts, mask2d, rcidx, starts, ends, flag, N, P);
    loss_kernel<<<M, THREADS, 0, stream>>>(start_offset, end_offset, tgt_moments,
                                           scatter, iou2ds, rcidx, starts, ends,
                                           psum, pcnt, flag, P, M, N);
    finalize_kernel<<<1, 256, 0, stream>>>(psum, pcnt, M, (float*)d_out);
}